// Round 10
// baseline (242.474 us; speedup 1.0000x reference)
//
#include <hip/hip_runtime.h>

// B=8, H=W=48 -> 2304 positions, C=256 channels.
// raw[b,ij,kl] = sum_c A[b,ij,c]*B[b,kl,c]
// out = raw / sqrt(sum_ij raw^2)     (reference's 1/C cancels in the norm)
//
// R12: R11 (fused single-GEMM, 1024 persistent blocks, best-tied 237.97)
// with ONE change: output stores are NONTEMPORAL. The 170 MB write-once
// output was streaming through the 32 MB L2, evicting the A/B input panels
// (R11 FETCH_SIZE 61 MB vs 19 MB of inputs; R8@512blk was 33 MB) and
// competing with staging fills. nt stores bypass L2 allocation: inputs stay
// resident, write stream drains straight to HBM.
// Sync logic byte-identical to R8/R11 (RMW-only, twice verified).

#define HW2 2304
#define CH  256
#define NB  8
#define NELEM (NB * HW2 * CH)   // 4,718,592 per input
#define NTILE 2592              // 18*18*8 tiles of 128x128
#define NGRP  144               // NB*18 column groups, 18 members each
#define PBLK  1024              // persistent blocks (4/CU, co-resident)

typedef __attribute__((ext_vector_type(8))) short bf16x8;   // 8 bf16 = 4 VGPRs
typedef __attribute__((ext_vector_type(4))) float f32x4;    // MFMA acc

static __device__ inline unsigned short f2bf(float f) {
    union { float f; unsigned u; } x; x.f = f;
    unsigned r = x.u + 0x7FFFu + ((x.u >> 16) & 1u);
    return (unsigned short)(r >> 16);
}

// async global->LDS, 16B per lane (global_load_lds_dwordx4)
static __device__ inline void async_copy16(const void* g, void* l) {
    __builtin_amdgcn_global_load_lds(
        (const __attribute__((address_space(1))) unsigned int*)g,
        (__attribute__((address_space(3))) unsigned int*)l, 16, 0, 0);
}

// ---------------------------------------------------------------------------
// 1. convert: fp32 -> bf16 (A,B row-major) + zero colSqG/cnt for this iter.
// ---------------------------------------------------------------------------
__global__ __launch_bounds__(256) void convert_bf16(const float* __restrict__ A,
                                                    const float* __restrict__ B,
                                                    unsigned short* __restrict__ Abf,
                                                    unsigned short* __restrict__ Bbf,
                                                    float* __restrict__ colSqG,
                                                    int* __restrict__ cnt) {
    const int gidx = blockIdx.x * blockDim.x + threadIdx.x;
    if (gidx < NB * HW2) colSqG[gidx] = 0.0f;     // 18432 floats
    if (gidx < NGRP) cnt[gidx] = 0;
    const int n4 = NELEM / 4;
    for (int i = gidx; i < 2 * n4; i += gridDim.x * blockDim.x) {
        const bool isA = i < n4;
        const int j = isA ? i : i - n4;
        float4 v = (isA ? (const float4*)A : (const float4*)B)[j];
        ushort4 p;
        p.x = f2bf(v.x); p.y = f2bf(v.y); p.z = f2bf(v.z); p.w = f2bf(v.w);
        *(ushort4*)((isA ? Abf : Bbf) + (size_t)j * 4) = p;
    }
}

// ---------------------------------------------------------------------------
// 2a. fused corr: 1024 persistent blocks; per tile: R2-proven GEMM ->
//     colSq RMWs -> group-counter sync -> RMW-fetch colSq -> normalize.
//     Output stores NONTEMPORAL (bypass L2 -> keep input panels resident).
// ---------------------------------------------------------------------------
__global__ __launch_bounds__(256, 4) void corr_fused(const unsigned short* __restrict__ Abf,
                                                     const unsigned short* __restrict__ Bbf,
                                                     float* __restrict__ colSqG,
                                                     int* __restrict__ cnt,
                                                     float* __restrict__ out) {
    __shared__ unsigned short As[2 * 128 * 32];   // 16 KB
    __shared__ unsigned short Bs[2 * 128 * 32];   // 16 KB
    __shared__ float colSq[128];

    const int tid = threadIdx.x;
    const int srow  = tid >> 2;
    const int skcol = (tid & 3) * 8;
    const int wave = tid >> 6, lane = tid & 63;
    const int wm = (wave >> 1) * 64, wn = (wave & 1) * 64;
    const int lr = lane & 15, quad = lane >> 4, k8 = quad * 8;

    // group-major identity mapping: consecutive tiles = same (b,bx) group,
    // so a straddler group's missing members are the first tiles of the
    // next round (completed first -> minimal spin).
    for (int t = blockIdx.x; t < NTILE; t += PBLK) {
        const int g  = t / 18;        // group = (b, bx): shared denominator
        const int by = t % 18;        // member = row tile
        const int b  = g / 18;
        const int bx = g % 18;

        const unsigned short* Ab = Abf + ((size_t)b * HW2 + (size_t)by * 128) * CH;
        const unsigned short* Bb = Bbf + ((size_t)b * HW2 + (size_t)bx * 128) * CH;

        if (tid < 128) colSq[tid] = 0.0f;

        f32x4 acc[4][4];
#pragma unroll
        for (int mi = 0; mi < 4; mi++)
#pragma unroll
            for (int nj = 0; nj < 4; nj++) acc[mi][nj] = (f32x4){0.f, 0.f, 0.f, 0.f};

        for (int kt = 0; kt < CH; kt += 64) {
#pragma unroll
            for (int c = 0; c < 2; c++) {
                const int kof = kt + c * 32;
#pragma unroll
                for (int ii = 0; ii < 2; ii++) {
                    async_copy16(Ab + (size_t)(srow + ii * 64) * CH + kof + skcol,
                                 &As[c * 4096 + tid * 8 + ii * 2048]);
                    async_copy16(Bb + (size_t)(srow + ii * 64) * CH + kof + skcol,
                                 &Bs[c * 4096 + tid * 8 + ii * 2048]);
                }
            }
            __syncthreads();   // vmcnt(0) drain + barrier
#pragma unroll
            for (int c = 0; c < 2; c++) {
                bf16x8 af[4], bfr[4];
#pragma unroll
                for (int mt = 0; mt < 4; mt++)
                    af[mt] = *(const bf16x8*)&As[c * 4096 + (wm + mt * 16 + lr) * 32 + k8];
#pragma unroll
                for (int nt = 0; nt < 4; nt++)
                    bfr[nt] = *(const bf16x8*)&Bs[c * 4096 + (wn + nt * 16 + lr) * 32 + k8];
#pragma unroll
                for (int mt = 0; mt < 4; mt++)
#pragma unroll
                    for (int nt = 0; nt < 4; nt++)
                        acc[mt][nt] = __builtin_amdgcn_mfma_f32_16x16x32_bf16(
                            af[mt], bfr[nt], acc[mt][nt], 0, 0, 0);
            }
            __syncthreads();
        }

        // ---- per-column sum of squares -> LDS -> one global RMW per column
#pragma unroll
        for (int nt = 0; nt < 4; nt++) {
            float s = 0.f;
#pragma unroll
            for (int mt = 0; mt < 4; mt++) {
                f32x4 v = acc[mt][nt];
#pragma unroll
                for (int r = 0; r < 4; r++) s += v[r] * v[r];
            }
            s += __shfl_xor(s, 16);
            s += __shfl_xor(s, 32);
            if (quad == 0) atomicAdd(&colSq[wn + nt * 16 + lr], s);
        }
        __syncthreads();
        if (tid < 128)
            atomicAdd(&colSqG[(size_t)b * HW2 + bx * 128 + tid], colSq[tid]);
        // barrier: every wave drains vmcnt before s_barrier -> all 128 RMWs
        // complete at the coherence point before tid0 bumps cnt.
        __syncthreads();

        // ---- group sync: wait until all 18 row-blocks of (b,bx) contributed
        if (tid == 0) {
            __hip_atomic_fetch_add(&cnt[g], 1, __ATOMIC_ACQ_REL,
                                   __HIP_MEMORY_SCOPE_AGENT);
            while (__hip_atomic_load(&cnt[g], __ATOMIC_ACQUIRE,
                                     __HIP_MEMORY_SCOPE_AGENT) < 18)
                __builtin_amdgcn_s_sleep(8);
        }
        __syncthreads();

        // ---- fetch final colSq via RMW (+0.0f): serializes at the coherence
        // point, cannot read a stale cached line.
        if (tid < 128)
            colSq[tid] = __hip_atomic_fetch_add(
                &colSqG[(size_t)b * HW2 + bx * 128 + tid], 0.0f,
                __ATOMIC_RELAXED, __HIP_MEMORY_SCOPE_AGENT);
        __syncthreads();

        // ---- normalize from registers and write (NONTEMPORAL: bypass L2)
        const size_t outBase = (size_t)b * HW2 * HW2;
#pragma unroll
        for (int nt = 0; nt < 4; nt++) {
            const int colL = wn + nt * 16 + lr;
            const int col  = bx * 128 + colL;
            const float rinv = rsqrtf(colSq[colL]);
#pragma unroll
            for (int mt = 0; mt < 4; mt++) {
                const int row0 = by * 128 + wm + mt * 16 + quad * 4;
                f32x4 v = acc[mt][nt];
#pragma unroll
                for (int r = 0; r < 4; r++)
                    __builtin_nontemporal_store(
                        v[r] * rinv,
                        &out[outBase + (size_t)(row0 + r) * HW2 + col]);
            }
        }
        __syncthreads();   // colSq LDS reuse safety before next tile's zeroing
    }
}

// ---------------------------------------------------------------------------
// 2b. fallback: R2's proven two-pass corr (no inter-block sync). Used only
//     if the occupancy tripwire reports <4 blocks/CU for corr_fused.
// ---------------------------------------------------------------------------
template <bool WRITE_OUT>
__global__ __launch_bounds__(256) void corr_pass(const unsigned short* __restrict__ Abf,
                                                 const unsigned short* __restrict__ Bbf,
                                                 float* __restrict__ colSqG,
                                                 float* __restrict__ out) {
    __shared__ unsigned short As[2 * 128 * 32];
    __shared__ unsigned short Bs[2 * 128 * 32];
    __shared__ float colSq[128];

    const int tid = threadIdx.x;
    const int lin = blockIdx.x + 18 * (blockIdx.y + 18 * blockIdx.z);
    const int b  = lin & 7;
    const int r_ = lin >> 3;
    const int bx = r_ % 18;
    const int by = r_ / 18;

    if (!WRITE_OUT && tid < 128) colSq[tid] = 0.0f;

    const unsigned short* Ab = Abf + ((size_t)b * HW2 + (size_t)by * 128) * CH;
    const unsigned short* Bb = Bbf + ((size_t)b * HW2 + (size_t)bx * 128) * CH;

    const int srow  = tid >> 2;
    const int skcol = (tid & 3) * 8;
    const int wave = tid >> 6, lane = tid & 63;
    const int wm = (wave >> 1) * 64, wn = (wave & 1) * 64;
    const int lr = lane & 15, quad = lane >> 4, k8 = quad * 8;

    f32x4 acc[4][4];
#pragma unroll
    for (int i = 0; i < 4; i++)
#pragma unroll
        for (int j = 0; j < 4; j++) acc[i][j] = (f32x4){0.f, 0.f, 0.f, 0.f};

    for (int kt = 0; kt < CH; kt += 64) {
#pragma unroll
        for (int c = 0; c < 2; c++) {
            const int kof = kt + c * 32;
#pragma unroll
            for (int i = 0; i < 2; i++) {
                async_copy16(Ab + (size_t)(srow + i * 64) * CH + kof + skcol,
                             &As[c * 4096 + tid * 8 + i * 2048]);
                async_copy16(Bb + (size_t)(srow + i * 64) * CH + kof + skcol,
                             &Bs[c * 4096 + tid * 8 + i * 2048]);
            }
        }
        __syncthreads();
#pragma unroll
        for (int c = 0; c < 2; c++) {
            bf16x8 af[4], bfr[4];
#pragma unroll
            for (int mt = 0; mt < 4; mt++)
                af[mt] = *(const bf16x8*)&As[c * 4096 + (wm + mt * 16 + lr) * 32 + k8];
#pragma unroll
            for (int nt = 0; nt < 4; nt++)
                bfr[nt] = *(const bf16x8*)&Bs[c * 4096 + (wn + nt * 16 + lr) * 32 + k8];
#pragma unroll
            for (int mt = 0; mt < 4; mt++)
#pragma unroll
                for (int nt = 0; nt < 4; nt++)
                    acc[mt][nt] = __builtin_amdgcn_mfma_f32_16x16x32_bf16(
                        af[mt], bfr[nt], acc[mt][nt], 0, 0, 0);
        }
        __syncthreads();
    }

    const int colBase = bx * 128 + wn;
    if (!WRITE_OUT) {
#pragma unroll
        for (int nt = 0; nt < 4; nt++) {
            float s = 0.f;
#pragma unroll
            for (int mt = 0; mt < 4; mt++) {
                f32x4 v = acc[mt][nt];
#pragma unroll
                for (int r = 0; r < 4; r++) s += v[r] * v[r];
            }
            s += __shfl_xor(s, 16);
            s += __shfl_xor(s, 32);
            if (quad == 0) atomicAdd(&colSq[wn + nt * 16 + lr], s);
        }
        __syncthreads();
        if (tid < 128)
            atomicAdd(&colSqG[(size_t)b * HW2 + bx * 128 + tid], colSq[tid]);
    } else {
        const size_t outBase = (size_t)b * HW2 * HW2;
#pragma unroll
        for (int nt = 0; nt < 4; nt++) {
            const int col = colBase + nt * 16 + lr;
            const float rinv = rsqrtf(colSqG[(size_t)b * HW2 + col]);
#pragma unroll
            for (int mt = 0; mt < 4; mt++) {
                const int row0 = by * 128 + wm + mt * 16 + quad * 4;
                f32x4 v = acc[mt][nt];
#pragma unroll
                for (int r = 0; r < 4; r++)
                    __builtin_nontemporal_store(
                        v[r] * rinv,
                        &out[outBase + (size_t)(row0 + r) * HW2 + col]);
            }
        }
    }
}

extern "C" void kernel_launch(void* const* d_in, const int* in_sizes, int n_in,
                              void* d_out, int out_size, void* d_ws, size_t ws_size,
                              hipStream_t stream) {
    const float* A = (const float*)d_in[0];
    const float* B = (const float*)d_in[1];
    float* out = (float*)d_out;

    unsigned short* Abf = (unsigned short*)d_ws;           // NELEM bf16
    unsigned short* Bbf = Abf + NELEM;                     // NELEM bf16
    float* colSqG = (float*)(Bbf + NELEM);                 // NB*HW2 f32
    int* cnt = (int*)(colSqG + (size_t)NB * HW2);          // NGRP ints

    // Occupancy tripwire: fused path requires 4 co-resident blocks/CU
    // (1024-block grid). launch_bounds(256,4) + 33KB LDS guarantee it;
    // the query guards against a surprise regression.
    static int occ = -1;
    if (occ < 0) {
        int n = 0;
        hipError_t e = hipOccupancyMaxActiveBlocksPerMultiprocessor(
            &n, (const void*)corr_fused, 256, 0);
        occ = (e == hipSuccess) ? n : 4;   // on query failure trust the static bound
    }

    convert_bf16<<<2048, 256, 0, stream>>>(A, B, Abf, Bbf, colSqG, cnt);

    if (occ >= 4) {
        corr_fused<<<PBLK, 256, 0, stream>>>(Abf, Bbf, colSqG, cnt, out);
    } else {
        dim3 grid(HW2 / 128, HW2 / 128, NB);   // 18 x 18 x 8
        corr_pass<false><<<grid, 256, 0, stream>>>(Abf, Bbf, colSqG, out);
        corr_pass<true><<<grid, 256, 0, stream>>>(Abf, Bbf, colSqG, out);
    }
}